// Round 2
// baseline (14033.676 us; speedup 1.0000x reference)
//
#include <hip/hip_runtime.h>
#include <cstdint>

typedef unsigned short u16;
typedef __bf16 bf16x8 __attribute__((ext_vector_type(8)));
typedef float f32x4 __attribute__((ext_vector_type(4)));

__device__ __forceinline__ float b2f(u16 u) { return __uint_as_float(((unsigned)u) << 16); }
__device__ __forceinline__ float lo16(unsigned u) { return __uint_as_float(u << 16); }
__device__ __forceinline__ float hi16(unsigned u) { return __uint_as_float(u & 0xFFFF0000u); }
__device__ __forceinline__ u16 f2b(float f) {
  unsigned u = __float_as_uint(f);
  return (u16)((u + 0x7FFFu + ((u >> 16) & 1u)) >> 16);
}

#define GLDS(g, l) __builtin_amdgcn_global_load_lds( \
    (const __attribute__((address_space(1))) void*)(g), \
    (__attribute__((address_space(3))) void*)(l), 16, 0, 0)

// ---------------- elementwise ----------------
__global__ __launch_bounds__(256) void addpe_kernel(const float* __restrict__ x,
                                                    const float* __restrict__ pe,
                                                    float* __restrict__ h) {
  int i = blockIdx.x * 256 + threadIdx.x;          // one float4 / thread
  float4 xv = ((const float4*)x)[i];
  float4 pv = ((const float4*)pe)[i & 0x1FFFF];    // S*D/4 = 131072
  float4 o;
  o.x = xv.x + pv.x; o.y = xv.y + pv.y; o.z = xv.z + pv.z; o.w = xv.w + pv.w;
  ((float4*)h)[i] = o;
}

__global__ __launch_bounds__(256) void copy_kernel(const float* __restrict__ h,
                                                   float* __restrict__ out) {
  int i = blockIdx.x * 256 + threadIdx.x;
  ((float4*)out)[i] = ((const float4*)h)[i];
}

// ---------------- layernorm (f32 in -> bf16 out), 1 block per row ----------------
__global__ __launch_bounds__(256) void ln_kernel(const float* __restrict__ in,
                                                 const float* __restrict__ g,
                                                 const float* __restrict__ bta,
                                                 u16* __restrict__ out) {
  int row = blockIdx.x, t = threadIdx.x;
  const float4 v = ((const float4*)(in + (size_t)row * 1024))[t];
  float s = v.x + v.y + v.z + v.w;
  float s2 = v.x * v.x + v.y * v.y + v.z * v.z + v.w * v.w;
#pragma unroll
  for (int off = 32; off > 0; off >>= 1) { s += __shfl_xor(s, off); s2 += __shfl_xor(s2, off); }
  __shared__ __align__(16) float red[8];
  int w = t >> 6;
  if ((t & 63) == 0) { red[w] = s; red[4 + w] = s2; }
  __syncthreads();
  s = red[0] + red[1] + red[2] + red[3];
  s2 = red[4] + red[5] + red[6] + red[7];
  float mu = s * (1.0f / 1024.0f);
  float var = s2 * (1.0f / 1024.0f) - mu * mu;
  float rstd = rsqrtf(var + 1e-6f);
  float4 gv = ((const float4*)g)[t];
  float4 bv = ((const float4*)bta)[t];
  ushort4 o;
  o.x = f2b((v.x - mu) * rstd * gv.x + bv.x);
  o.y = f2b((v.y - mu) * rstd * gv.y + bv.y);
  o.z = f2b((v.z - mu) * rstd * gv.z + bv.z);
  o.w = f2b((v.w - mu) * rstd * gv.w + bv.w);
  ((ushort4*)(out + (size_t)row * 1024))[t] = o;
}

// ---------------- weight transpose + f32->bf16: src[K][N] f32 -> dst[N][K] bf16 ----------------
__global__ __launch_bounds__(256) void transpose_kernel(const float* __restrict__ src,
                                                        u16* __restrict__ dst,
                                                        int K, int N) {
  __shared__ __align__(16) float tile[32][33];
  int n0 = blockIdx.x * 32, k0 = blockIdx.y * 32;
  int tx = threadIdx.x, ty = threadIdx.y;  // 32 x 8
#pragma unroll
  for (int j = 0; j < 4; j++)
    tile[ty + j * 8][tx] = src[(size_t)(k0 + ty + j * 8) * N + n0 + tx];
  __syncthreads();
#pragma unroll
  for (int j = 0; j < 4; j++)
    dst[(size_t)(n0 + ty + j * 8) * K + k0 + tx] = f2b(tile[tx][ty + j * 8]);
}

// ---------------- GEMM: C[M,N] = A[M,K] @ Wt[N,K]^T + bias, fused epilogues ----------------
// EPI 0: Cb = bf16(acc+bias)            (q,k,v proj)
// EPI 1: Cb = bf16(gelu(acc+bias))      (ffn w1, exact erf gelu)
// EPI 2: F  = R + acc+bias              (wo: out1 = h + attn)
// EPI 3: F  = F + R + acc+bias          (w2: h = h + out1 + ffn)
template <int EPI>
__global__ __launch_bounds__(256) void gemm_bt(const u16* __restrict__ A,
                                               const u16* __restrict__ Wt,
                                               const float* __restrict__ bias,
                                               u16* __restrict__ Cb,
                                               const float* __restrict__ R,
                                               float* __restrict__ F,
                                               int M, int N, int K) {
  __shared__ __align__(16) u16 Asm[128 * 32];
  __shared__ __align__(16) u16 Bsm[128 * 32];
  int t = threadIdx.x;
  int w = t >> 6, lane = t & 63;
  int wm = w >> 1, wn = w & 1;
  int m0 = blockIdx.y * 128, n0 = blockIdx.x * 128;
  int r = t >> 2, c = (t & 3) * 8;
  const u16* Ap = A + (size_t)(m0 + r) * K + c;
  const u16* Bp = Wt + (size_t)(n0 + r) * K + c;
  u16* AsmW = Asm + w * 512;  // wave-uniform LDS base; HW adds lane*16B
  u16* BsmW = Bsm + w * 512;
  f32x4 acc[4][4] = {};
  int lrow = lane & 15, kq = (lane >> 4) * 8;
  for (int k0 = 0; k0 < K; k0 += 32) {
    __syncthreads();
    GLDS(Ap, AsmW); GLDS(Ap + (size_t)64 * K, AsmW + 2048);
    GLDS(Bp, BsmW); GLDS(Bp + (size_t)64 * K, BsmW + 2048);
    Ap += 32; Bp += 32;
    __syncthreads();
    bf16x8 af[4], bfr[4];
#pragma unroll
    for (int mi = 0; mi < 4; mi++)
      af[mi] = *(const bf16x8*)(Asm + (wm * 64 + mi * 16 + lrow) * 32 + kq);
#pragma unroll
    for (int ni = 0; ni < 4; ni++)
      bfr[ni] = *(const bf16x8*)(Bsm + (wn * 64 + ni * 16 + lrow) * 32 + kq);
#pragma unroll
    for (int mi = 0; mi < 4; mi++)
#pragma unroll
      for (int ni = 0; ni < 4; ni++)
        acc[mi][ni] = __builtin_amdgcn_mfma_f32_16x16x32_bf16(af[mi], bfr[ni], acc[mi][ni], 0, 0, 0);
  }
  int cm = m0 + wm * 64, cn = n0 + wn * 64;
  int rq = (lane >> 4) * 4, cq = lane & 15;
#pragma unroll
  for (int ni = 0; ni < 4; ni++) {
    int col = cn + ni * 16 + cq;
    float bv = bias[col];
#pragma unroll
    for (int mi = 0; mi < 4; mi++) {
      int row = cm + mi * 16 + rq;
#pragma unroll
      for (int rr = 0; rr < 4; rr++) {
        size_t idx = (size_t)(row + rr) * N + col;
        float v = acc[mi][ni][rr] + bv;
        if constexpr (EPI == 0) {
          Cb[idx] = f2b(v);
        } else if constexpr (EPI == 1) {
          Cb[idx] = f2b(0.5f * v * (1.0f + erff(v * 0.70710678118f)));
        } else if constexpr (EPI == 2) {
          F[idx] = R[idx] + v;
        } else {
          F[idx] = F[idx] + R[idx] + v;
        }
      }
    }
  }
}

// ---------------- flash attention w/ relative position bias ----------------
// grid: (S/32, H, B); block 256 = 4 waves; wave w owns 8 q-rows; lane owns dim d=lane.
__global__ __launch_bounds__(256) void attn_kernel(const u16* __restrict__ Q,
                                                   const u16* __restrict__ Kg,
                                                   const u16* __restrict__ Vg,
                                                   const float* __restrict__ bt,
                                                   u16* __restrict__ ctx) {
  __shared__ __align__(16) u16 Ks[128 * 66];    // K[kk][d] pad-66  -> conflict-free b32 over d
  __shared__ __align__(16) u16 Vs[64 * 130];    // V^T[d][kk] pad-130 -> conflict-free b32 over kk
  __shared__ __align__(16) u16 Qs[32 * 66];
  __shared__ __align__(16) float bias_s[1023];
  __shared__ __align__(16) float p_s[4][128];
  int t = threadIdx.x, w = t >> 6, lane = t & 63;
  int q0 = blockIdx.x * 32, h = blockIdx.y, b = blockIdx.z;
  size_t base = ((size_t)b * 512) * 1024 + (size_t)h * 64;  // + s*1024 + d
  for (int e = t; e < 32 * 64; e += 256) {
    int rr = e >> 6, d = e & 63;
    Qs[rr * 66 + d] = Q[base + (size_t)(q0 + rr) * 1024 + d];
  }
  for (int e = t; e < 1023; e += 256) bias_s[e] = bt[e * 16 + h];
  float m_st[8], l_st[8], O[8];
#pragma unroll
  for (int i = 0; i < 8; i++) { m_st[i] = -1e30f; l_st[i] = 0.f; O[i] = 0.f; }
  const unsigned* Ks32 = (const unsigned*)Ks;
  const unsigned* Vs32 = (const unsigned*)Vs;
  const unsigned* Qs32 = (const unsigned*)Qs;
  for (int kt = 0; kt < 4; kt++) {
    __syncthreads();
    for (int e = t; e < 128 * 64; e += 256) {
      int kk = e >> 6, d = e & 63;
      size_t gidx = base + (size_t)(kt * 128 + kk) * 1024 + d;
      Ks[kk * 66 + d] = Kg[gidx];
      Vs[d * 130 + kk] = Vg[gidx];
    }
    __syncthreads();
#pragma unroll
    for (int rr = 0; rr < 8; rr++) {
      int rloc = w * 8 + rr;
      float s0 = 0.f, s1 = 0.f;
      const unsigned* qrow = Qs32 + rloc * 33;
      const unsigned* k0r = Ks32 + lane * 33;
      const unsigned* k1r = Ks32 + (64 + lane) * 33;
      for (int d2 = 0; d2 < 32; d2++) {
        unsigned qp = qrow[d2];
        unsigned kp0 = k0r[d2], kp1 = k1r[d2];
        float ql = lo16(qp), qh = hi16(qp);
        s0 += ql * lo16(kp0) + qh * hi16(kp0);
        s1 += ql * lo16(kp1) + qh * hi16(kp1);
      }
      int qg = q0 + rloc;
      int kg = kt * 128 + lane;
      s0 = s0 * 0.125f + bias_s[qg - kg + 511];
      s1 = s1 * 0.125f + bias_s[qg - kg + 447];  // key kg+64
      float mt = fmaxf(s0, s1);
#pragma unroll
      for (int off = 32; off > 0; off >>= 1) mt = fmaxf(mt, __shfl_xor(mt, off));
      float mnew = fmaxf(m_st[rr], mt);
      float alpha = __expf(m_st[rr] - mnew);
      float p0 = __expf(s0 - mnew), p1 = __expf(s1 - mnew);
      float ps = p0 + p1;
#pragma unroll
      for (int off = 32; off > 0; off >>= 1) ps += __shfl_xor(ps, off);
      m_st[rr] = mnew;
      l_st[rr] = l_st[rr] * alpha + ps;
      p_s[w][lane] = p0;
      p_s[w][64 + lane] = p1;
      float o = O[rr] * alpha;
      const float2* pr = (const float2*)p_s[w];
      const unsigned* vr = Vs32 + lane * 65;
      for (int k2 = 0; k2 < 64; k2++) {
        float2 pp = pr[k2];
        unsigned vv = vr[k2];
        o += pp.x * lo16(vv) + pp.y * hi16(vv);
      }
      O[rr] = o;
    }
  }
#pragma unroll
  for (int rr = 0; rr < 8; rr++) {
    int rloc = w * 8 + rr;
    ctx[base + (size_t)(q0 + rloc) * 1024 + lane] = f2b(O[rr] / l_st[rr]);
  }
}

// ---------------- driver ----------------
extern "C" void kernel_launch(void* const* d_in, const int* in_sizes, int n_in,
                              void* d_out, int out_size, void* d_ws, size_t ws_size,
                              hipStream_t stream) {
  (void)in_sizes; (void)n_in; (void)out_size; (void)ws_size;
  const float* x = (const float*)d_in[0];
  const float* pe = (const float*)d_in[1];
  const float* wq = (const float*)d_in[2];
  const float* bq = (const float*)d_in[3];
  const float* wk = (const float*)d_in[4];
  const float* bk = (const float*)d_in[5];
  const float* wv = (const float*)d_in[6];
  const float* bvv = (const float*)d_in[7];
  const float* wo = (const float*)d_in[8];
  const float* bo = (const float*)d_in[9];
  const float* btab = (const float*)d_in[10];
  const float* w1 = (const float*)d_in[11];
  const float* b1 = (const float*)d_in[12];
  const float* w2 = (const float*)d_in[13];
  const float* b2 = (const float*)d_in[14];
  const float* ln1g = (const float*)d_in[15];
  const float* ln1b = (const float*)d_in[16];
  const float* ln2g = (const float*)d_in[17];
  const float* ln2b = (const float*)d_in[18];

  const int M = 8192, D = 1024, F = 4096;
  char* p = (char*)d_ws;
  float* h = (float*)p;  p += (size_t)M * D * 4;   // 32 MB
  float* o1 = (float*)p; p += (size_t)M * D * 4;   // 32 MB
  u16* xn = (u16*)p;     p += (size_t)M * D * 2;   // 16 MB
  u16* qb = (u16*)p;     p += (size_t)M * D * 2;   // 16 MB
  u16* kb = (u16*)p;     p += (size_t)M * D * 2;   // 16 MB
  u16* vb = (u16*)p;     p += (size_t)M * D * 2;   // 16 MB
  u16* ctx = (u16*)p;    p += (size_t)M * D * 2;   // 16 MB
  u16* mid = qb;  // aliases qb..ctx (64 MB), dead by the time mid is written
  u16* wtq = (u16*)p;    p += (size_t)D * D * 2;
  u16* wtk = (u16*)p;    p += (size_t)D * D * 2;
  u16* wtv = (u16*)p;    p += (size_t)D * D * 2;
  u16* wto = (u16*)p;    p += (size_t)D * D * 2;
  u16* wt1 = (u16*)p;    p += (size_t)D * F * 2;
  u16* wt2 = (u16*)p;    p += (size_t)F * D * 2;

  addpe_kernel<<<8192, 256, 0, stream>>>(x, pe, h);
  for (int i = 0; i < 6; i++) {
    ln_kernel<<<M, 256, 0, stream>>>(h, ln1g + i * D, ln1b + i * D, xn);
    transpose_kernel<<<dim3(D / 32, D / 32), dim3(32, 8), 0, stream>>>(wq + (size_t)i * D * D, wtq, D, D);
    transpose_kernel<<<dim3(D / 32, D / 32), dim3(32, 8), 0, stream>>>(wk + (size_t)i * D * D, wtk, D, D);
    transpose_kernel<<<dim3(D / 32, D / 32), dim3(32, 8), 0, stream>>>(wv + (size_t)i * D * D, wtv, D, D);
    transpose_kernel<<<dim3(D / 32, D / 32), dim3(32, 8), 0, stream>>>(wo + (size_t)i * D * D, wto, D, D);
    transpose_kernel<<<dim3(F / 32, D / 32), dim3(32, 8), 0, stream>>>(w1 + (size_t)i * D * F, wt1, D, F);
    transpose_kernel<<<dim3(D / 32, F / 32), dim3(32, 8), 0, stream>>>(w2 + (size_t)i * F * D, wt2, F, D);
    gemm_bt<0><<<dim3(D / 128, M / 128), 256, 0, stream>>>(xn, wtq, bq + i * D, qb, nullptr, nullptr, M, D, D);
    gemm_bt<0><<<dim3(D / 128, M / 128), 256, 0, stream>>>(xn, wtk, bk + i * D, kb, nullptr, nullptr, M, D, D);
    gemm_bt<0><<<dim3(D / 128, M / 128), 256, 0, stream>>>(xn, wtv, bvv + i * D, vb, nullptr, nullptr, M, D, D);
    attn_kernel<<<dim3(16, 16, 16), 256, 0, stream>>>(qb, kb, vb, btab + (size_t)i * 1023 * 16, ctx);
    gemm_bt<2><<<dim3(D / 128, M / 128), 256, 0, stream>>>(ctx, wto, bo + i * D, nullptr, h, o1, M, D, D);
    ln_kernel<<<M, 256, 0, stream>>>(o1, ln2g + i * D, ln2b + i * D, xn);
    gemm_bt<1><<<dim3(F / 128, M / 128), 256, 0, stream>>>(xn, wt1, b1 + i * F, mid, nullptr, nullptr, M, F, D);
    gemm_bt<3><<<dim3(D / 128, M / 128), 256, 0, stream>>>(mid, wt2, b2 + i * D, nullptr, o1, h, M, D, F);
  }
  copy_kernel<<<8192, 256, 0, stream>>>(h, (float*)d_out);
}

// Round 3
// 3225.074 us; speedup vs baseline: 4.3514x; 4.3514x over previous
//
#include <hip/hip_runtime.h>
#include <cstdint>

typedef unsigned short u16;
typedef __bf16 bf16x8 __attribute__((ext_vector_type(8)));
typedef unsigned short u16x8 __attribute__((ext_vector_type(8)));
typedef float f32x4 __attribute__((ext_vector_type(4)));

__device__ __forceinline__ float b2f(u16 u) { return __uint_as_float(((unsigned)u) << 16); }
__device__ __forceinline__ u16 f2b(float f) {
  unsigned u = __float_as_uint(f);
  return (u16)((u + 0x7FFFu + ((u >> 16) & 1u)) >> 16);
}

#define GLDS(g, l) __builtin_amdgcn_global_load_lds( \
    (const __attribute__((address_space(1))) void*)(g), \
    (__attribute__((address_space(3))) void*)(l), 16, 0, 0)

// ---------------- elementwise ----------------
__global__ __launch_bounds__(256) void addpe_kernel(const float* __restrict__ x,
                                                    const float* __restrict__ pe,
                                                    float* __restrict__ h) {
  int i = blockIdx.x * 256 + threadIdx.x;          // one float4 / thread
  float4 xv = ((const float4*)x)[i];
  float4 pv = ((const float4*)pe)[i & 0x1FFFF];    // S*D/4 = 131072
  float4 o;
  o.x = xv.x + pv.x; o.y = xv.y + pv.y; o.z = xv.z + pv.z; o.w = xv.w + pv.w;
  ((float4*)h)[i] = o;
}

__global__ __launch_bounds__(256) void copy_kernel(const float* __restrict__ h,
                                                   float* __restrict__ out) {
  int i = blockIdx.x * 256 + threadIdx.x;
  ((float4*)out)[i] = ((const float4*)h)[i];
}

// ---------------- layernorm (f32 in -> bf16 out), 1 block per row ----------------
__global__ __launch_bounds__(256) void ln_kernel(const float* __restrict__ in,
                                                 const float* __restrict__ g,
                                                 const float* __restrict__ bta,
                                                 u16* __restrict__ out) {
  int row = blockIdx.x, t = threadIdx.x;
  const float4 v = ((const float4*)(in + (size_t)row * 1024))[t];
  float s = v.x + v.y + v.z + v.w;
  float s2 = v.x * v.x + v.y * v.y + v.z * v.z + v.w * v.w;
#pragma unroll
  for (int off = 32; off > 0; off >>= 1) { s += __shfl_xor(s, off); s2 += __shfl_xor(s2, off); }
  __shared__ __align__(16) float red[8];
  int w = t >> 6;
  if ((t & 63) == 0) { red[w] = s; red[4 + w] = s2; }
  __syncthreads();
  s = red[0] + red[1] + red[2] + red[3];
  s2 = red[4] + red[5] + red[6] + red[7];
  float mu = s * (1.0f / 1024.0f);
  float var = s2 * (1.0f / 1024.0f) - mu * mu;
  float rstd = rsqrtf(var + 1e-6f);
  float4 gv = ((const float4*)g)[t];
  float4 bv = ((const float4*)bta)[t];
  ushort4 o;
  o.x = f2b((v.x - mu) * rstd * gv.x + bv.x);
  o.y = f2b((v.y - mu) * rstd * gv.y + bv.y);
  o.z = f2b((v.z - mu) * rstd * gv.z + bv.z);
  o.w = f2b((v.w - mu) * rstd * gv.w + bv.w);
  ((ushort4*)(out + (size_t)row * 1024))[t] = o;
}

// ---------------- weight transpose + f32->bf16: src[K][N] f32 -> dst[N][K] bf16 ----------------
__global__ __launch_bounds__(256) void transpose_kernel(const float* __restrict__ src,
                                                        u16* __restrict__ dst,
                                                        int K, int N) {
  __shared__ __align__(16) float tile[32][33];
  int n0 = blockIdx.x * 32, k0 = blockIdx.y * 32;
  int tx = threadIdx.x, ty = threadIdx.y;  // 32 x 8
#pragma unroll
  for (int j = 0; j < 4; j++)
    tile[ty + j * 8][tx] = src[(size_t)(k0 + ty + j * 8) * N + n0 + tx];
  __syncthreads();
#pragma unroll
  for (int j = 0; j < 4; j++)
    dst[(size_t)(n0 + ty + j * 8) * K + k0 + tx] = f2b(tile[tx][ty + j * 8]);
}

// ---------------- GEMM: C[M,N] = A[M,K] @ Wt[N,K]^T + bias, fused epilogues ----------------
template <int EPI>
__global__ __launch_bounds__(256) void gemm_bt(const u16* __restrict__ A,
                                               const u16* __restrict__ Wt,
                                               const float* __restrict__ bias,
                                               u16* __restrict__ Cb,
                                               const float* __restrict__ R,
                                               float* __restrict__ F,
                                               int M, int N, int K) {
  __shared__ __align__(16) u16 Asm[128 * 32];
  __shared__ __align__(16) u16 Bsm[128 * 32];
  int t = threadIdx.x;
  int w = t >> 6, lane = t & 63;
  int wm = w >> 1, wn = w & 1;
  int m0 = blockIdx.y * 128, n0 = blockIdx.x * 128;
  int r = t >> 2, c = (t & 3) * 8;
  const u16* Ap = A + (size_t)(m0 + r) * K + c;
  const u16* Bp = Wt + (size_t)(n0 + r) * K + c;
  u16* AsmW = Asm + w * 512;  // wave-uniform LDS base; HW adds lane*16B
  u16* BsmW = Bsm + w * 512;
  f32x4 acc[4][4] = {};
  int lrow = lane & 15, kq = (lane >> 4) * 8;
  for (int k0 = 0; k0 < K; k0 += 32) {
    __syncthreads();
    GLDS(Ap, AsmW); GLDS(Ap + (size_t)64 * K, AsmW + 2048);
    GLDS(Bp, BsmW); GLDS(Bp + (size_t)64 * K, BsmW + 2048);
    Ap += 32; Bp += 32;
    __syncthreads();
    bf16x8 af[4], bfr[4];
#pragma unroll
    for (int mi = 0; mi < 4; mi++)
      af[mi] = *(const bf16x8*)(Asm + (wm * 64 + mi * 16 + lrow) * 32 + kq);
#pragma unroll
    for (int ni = 0; ni < 4; ni++)
      bfr[ni] = *(const bf16x8*)(Bsm + (wn * 64 + ni * 16 + lrow) * 32 + kq);
#pragma unroll
    for (int mi = 0; mi < 4; mi++)
#pragma unroll
      for (int ni = 0; ni < 4; ni++)
        acc[mi][ni] = __builtin_amdgcn_mfma_f32_16x16x32_bf16(af[mi], bfr[ni], acc[mi][ni], 0, 0, 0);
  }
  int cm = m0 + wm * 64, cn = n0 + wn * 64;
  int rq = (lane >> 4) * 4, cq = lane & 15;
#pragma unroll
  for (int ni = 0; ni < 4; ni++) {
    int col = cn + ni * 16 + cq;
    float bv = bias[col];
#pragma unroll
    for (int mi = 0; mi < 4; mi++) {
      int row = cm + mi * 16 + rq;
#pragma unroll
      for (int rr = 0; rr < 4; rr++) {
        size_t idx = (size_t)(row + rr) * N + col;
        float v = acc[mi][ni][rr] + bv;
        if constexpr (EPI == 0) {
          Cb[idx] = f2b(v);
        } else if constexpr (EPI == 1) {
          Cb[idx] = f2b(0.5f * v * (1.0f + erff(v * 0.70710678118f)));
        } else if constexpr (EPI == 2) {
          F[idx] = R[idx] + v;
        } else {
          F[idx] = F[idx] + R[idx] + v;
        }
      }
    }
  }
}

// ---------------- MFMA flash attention w/ relative position bias ----------------
// grid (S/64, H, B); block 256 = 4 waves; wave w owns q-rows [w*16, w*16+16).
// K-tiles of 128 keys. Q,K rows [s][d] stride 72; V transposed [d][k] stride 136.
// P (probs) round-trips through wave-private LDS: C-layout -> A-layout.
__global__ __launch_bounds__(256) void attn_mfma(const u16* __restrict__ Qg,
                                                 const u16* __restrict__ Kg,
                                                 const u16* __restrict__ Vg,
                                                 const float* __restrict__ bt,
                                                 u16* __restrict__ ctx) {
  __shared__ __align__(16) u16 Qs[64 * 72];
  __shared__ __align__(16) u16 Ks[128 * 72];
  __shared__ __align__(16) u16 Vts[64 * 136];
  __shared__ __align__(16) u16 Ps[64 * 136];
  __shared__ __align__(16) u16 bias_s[1023];
  int t = threadIdx.x, w = t >> 6, lane = t & 63;
  int l15 = lane & 15, quad = lane >> 4;
  int q0 = blockIdx.x * 64, h = blockIdx.y, b = blockIdx.z;
  size_t base = ((size_t)b * 512) * 1024 + (size_t)h * 64;  // + s*1024 + d

  {  // stage Q (64 rows x 64 d)
    int r = t >> 3, c = (t & 7) * 8;
    *(u16x8*)(Qs + r * 72 + c) = *(const u16x8*)(Qg + base + (size_t)(q0 + r) * 1024 + c);
    *(u16x8*)(Qs + (r + 32) * 72 + c) = *(const u16x8*)(Qg + base + (size_t)(q0 + r + 32) * 1024 + c);
  }
  for (int e = t; e < 1023; e += 256) bias_s[e] = f2b(bt[e * 16 + h]);

  float m_st[4], l_st[4];
  f32x4 O[4] = {};
#pragma unroll
  for (int i = 0; i < 4; i++) { m_st[i] = -1e30f; l_st[i] = 0.f; }

  __syncthreads();
  // Q A-fragments, kept in registers for the whole kernel
  bf16x8 aq0 = *(const bf16x8*)(Qs + (w * 16 + l15) * 72 + quad * 8);
  bf16x8 aq1 = *(const bf16x8*)(Qs + (w * 16 + l15) * 72 + 32 + quad * 8);

  for (int kt = 0; kt < 4; kt++) {
    if (kt) __syncthreads();  // prior tile's reads done before restage
    {  // stage K tile (128 rows x 64 d)
      int r = t >> 3, c = (t & 7) * 8;
#pragma unroll
      for (int p = 0; p < 4; p++)
        *(u16x8*)(Ks + (p * 32 + r) * 72 + c) =
            *(const u16x8*)(Kg + base + (size_t)(kt * 128 + p * 32 + r) * 1024 + c);
    }
    {  // stage V transposed: Vts[d][k], d = lane, k coalesced across lanes per load
#pragma unroll
      for (int p = 0; p < 4; p++) {
        u16x8 vv;
        int k8 = kt * 128 + p * 32 + w * 8;
#pragma unroll
        for (int j = 0; j < 8; j++) vv[j] = Vg[base + (size_t)(k8 + j) * 1024 + lane];
        *(u16x8*)(Vts + lane * 136 + p * 32 + w * 8) = vv;
      }
    }
    __syncthreads();

    // QK^T: 16 q-rows x 128 keys per wave
    f32x4 sc[8];
#pragma unroll
    for (int nt = 0; nt < 8; nt++) {
      bf16x8 bk0 = *(const bf16x8*)(Ks + (nt * 16 + l15) * 72 + quad * 8);
      bf16x8 bk1 = *(const bf16x8*)(Ks + (nt * 16 + l15) * 72 + 32 + quad * 8);
      f32x4 z = {};
      z = __builtin_amdgcn_mfma_f32_16x16x32_bf16(aq0, bk0, z, 0, 0, 0);
      sc[nt] = __builtin_amdgcn_mfma_f32_16x16x32_bf16(aq1, bk1, z, 0, 0, 0);
    }
    // scale + relative position bias
#pragma unroll
    for (int nt = 0; nt < 8; nt++) {
      int kg = kt * 128 + nt * 16 + l15;
#pragma unroll
      for (int rr = 0; rr < 4; rr++) {
        int qg = q0 + w * 16 + quad * 4 + rr;
        sc[nt][rr] = sc[nt][rr] * 0.125f + b2f(bias_s[qg - kg + 511]);
      }
    }
    // online softmax (row = 16-lane group)
#pragma unroll
    for (int rr = 0; rr < 4; rr++) {
      float mt = sc[0][rr];
#pragma unroll
      for (int nt = 1; nt < 8; nt++) mt = fmaxf(mt, sc[nt][rr]);
#pragma unroll
      for (int off = 8; off > 0; off >>= 1) mt = fmaxf(mt, __shfl_xor(mt, off));
      float mnew = fmaxf(m_st[rr], mt);
      float alpha = __expf(m_st[rr] - mnew);
      float ps = 0.f;
#pragma unroll
      for (int nt = 0; nt < 8; nt++) {
        float p = __expf(sc[nt][rr] - mnew);
        sc[nt][rr] = p;
        ps += p;
      }
#pragma unroll
      for (int off = 8; off > 0; off >>= 1) ps += __shfl_xor(ps, off);
      m_st[rr] = mnew;
      l_st[rr] = l_st[rr] * alpha + ps;
#pragma unroll
      for (int dt = 0; dt < 4; dt++) O[dt][rr] *= alpha;
      // write P row (C-layout -> LDS [q][k])
#pragma unroll
      for (int nt = 0; nt < 8; nt++)
        Ps[(w * 16 + quad * 4 + rr) * 136 + nt * 16 + l15] = f2b(sc[nt][rr]);
    }
    // PV: O[16 q][64 d] += P[16x128] * Vt
#pragma unroll
    for (int ks = 0; ks < 4; ks++) {
      bf16x8 ap = *(const bf16x8*)(Ps + (w * 16 + l15) * 136 + ks * 32 + quad * 8);
#pragma unroll
      for (int dt = 0; dt < 4; dt++) {
        bf16x8 bv = *(const bf16x8*)(Vts + (dt * 16 + l15) * 136 + ks * 32 + quad * 8);
        O[dt] = __builtin_amdgcn_mfma_f32_16x16x32_bf16(ap, bv, O[dt], 0, 0, 0);
      }
    }
  }
  // epilogue: O / l -> ctx
#pragma unroll
  for (int dt = 0; dt < 4; dt++) {
    int col = h * 64 + dt * 16 + l15;
#pragma unroll
    for (int rr = 0; rr < 4; rr++) {
      int row = q0 + w * 16 + quad * 4 + rr;
      ctx[((size_t)b * 512 + row) * 1024 + col] = f2b(O[dt][rr] / l_st[rr]);
    }
  }
}

// ---------------- driver ----------------
extern "C" void kernel_launch(void* const* d_in, const int* in_sizes, int n_in,
                              void* d_out, int out_size, void* d_ws, size_t ws_size,
                              hipStream_t stream) {
  (void)in_sizes; (void)n_in; (void)out_size; (void)ws_size;
  const float* x = (const float*)d_in[0];
  const float* pe = (const float*)d_in[1];
  const float* wq = (const float*)d_in[2];
  const float* bq = (const float*)d_in[3];
  const float* wk = (const float*)d_in[4];
  const float* bk = (const float*)d_in[5];
  const float* wv = (const float*)d_in[6];
  const float* bvv = (const float*)d_in[7];
  const float* wo = (const float*)d_in[8];
  const float* bo = (const float*)d_in[9];
  const float* btab = (const float*)d_in[10];
  const float* w1 = (const float*)d_in[11];
  const float* b1 = (const float*)d_in[12];
  const float* w2 = (const float*)d_in[13];
  const float* b2 = (const float*)d_in[14];
  const float* ln1g = (const float*)d_in[15];
  const float* ln1b = (const float*)d_in[16];
  const float* ln2g = (const float*)d_in[17];
  const float* ln2b = (const float*)d_in[18];

  const int M = 8192, D = 1024, F = 4096;
  char* p = (char*)d_ws;
  float* h = (float*)p;  p += (size_t)M * D * 4;   // 32 MB
  float* o1 = (float*)p; p += (size_t)M * D * 4;   // 32 MB
  u16* xn = (u16*)p;     p += (size_t)M * D * 2;   // 16 MB
  u16* qb = (u16*)p;     p += (size_t)M * D * 2;   // 16 MB
  u16* kb = (u16*)p;     p += (size_t)M * D * 2;   // 16 MB
  u16* vb = (u16*)p;     p += (size_t)M * D * 2;   // 16 MB
  u16* ctx = (u16*)p;    p += (size_t)M * D * 2;   // 16 MB
  u16* mid = qb;  // aliases qb..ctx (64 MB), dead by the time mid is written
  u16* wtq = (u16*)p;    p += (size_t)D * D * 2;
  u16* wtk = (u16*)p;    p += (size_t)D * D * 2;
  u16* wtv = (u16*)p;    p += (size_t)D * D * 2;
  u16* wto = (u16*)p;    p += (size_t)D * D * 2;
  u16* wt1 = (u16*)p;    p += (size_t)D * F * 2;
  u16* wt2 = (u16*)p;    p += (size_t)F * D * 2;

  addpe_kernel<<<8192, 256, 0, stream>>>(x, pe, h);
  for (int i = 0; i < 6; i++) {
    ln_kernel<<<M, 256, 0, stream>>>(h, ln1g + i * D, ln1b + i * D, xn);
    transpose_kernel<<<dim3(D / 32, D / 32), dim3(32, 8), 0, stream>>>(wq + (size_t)i * D * D, wtq, D, D);
    transpose_kernel<<<dim3(D / 32, D / 32), dim3(32, 8), 0, stream>>>(wk + (size_t)i * D * D, wtk, D, D);
    transpose_kernel<<<dim3(D / 32, D / 32), dim3(32, 8), 0, stream>>>(wv + (size_t)i * D * D, wtv, D, D);
    transpose_kernel<<<dim3(D / 32, D / 32), dim3(32, 8), 0, stream>>>(wo + (size_t)i * D * D, wto, D, D);
    transpose_kernel<<<dim3(F / 32, D / 32), dim3(32, 8), 0, stream>>>(w1 + (size_t)i * D * F, wt1, D, F);
    transpose_kernel<<<dim3(D / 32, F / 32), dim3(32, 8), 0, stream>>>(w2 + (size_t)i * F * D, wt2, F, D);
    gemm_bt<0><<<dim3(D / 128, M / 128), 256, 0, stream>>>(xn, wtq, bq + i * D, qb, nullptr, nullptr, M, D, D);
    gemm_bt<0><<<dim3(D / 128, M / 128), 256, 0, stream>>>(xn, wtk, bk + i * D, kb, nullptr, nullptr, M, D, D);
    gemm_bt<0><<<dim3(D / 128, M / 128), 256, 0, stream>>>(xn, wtv, bvv + i * D, vb, nullptr, nullptr, M, D, D);
    attn_mfma<<<dim3(8, 16, 16), 256, 0, stream>>>(qb, kb, vb, btab + (size_t)i * 1023 * 16, ctx);
    gemm_bt<2><<<dim3(D / 128, M / 128), 256, 0, stream>>>(ctx, wto, bo + i * D, nullptr, h, o1, M, D, D);
    ln_kernel<<<M, 256, 0, stream>>>(o1, ln2g + i * D, ln2b + i * D, xn);
    gemm_bt<1><<<dim3(F / 128, M / 128), 256, 0, stream>>>(xn, wt1, b1 + i * F, mid, nullptr, nullptr, M, F, D);
    gemm_bt<3><<<dim3(D / 128, M / 128), 256, 0, stream>>>(mid, wt2, b2 + i * D, nullptr, o1, h, M, D, F);
  }
  copy_kernel<<<8192, 256, 0, stream>>>(h, (float*)d_out);
}